// Round 11
// baseline (124.223 us; speedup 1.0000x reference)
//
#include <hip/hip_runtime.h>
#include <stdint.h>
#include <utility>

// PostProcessor3D: threshold(>0.9) + 5x5x5 stride-1 maxpool + strict-local-max
// mask on [64,512,512] fp32.
//
// R22: SINGLE-VARIABLE A/B vs R16 -- plain stores instead of nontemporal.
// Eleven-round post-mortem: cost is work-proportional (~1200-1500 CU-cyc per
// 64x16 slice-unit) across every sync scheme, prefetch depth, data path,
// occupancy (17-85%), and granularity; every throughput counter <50%
// (HBM 51%, L1-request ~65%, L2 12%, LDS 10%, VALU 25%). The limiter must be
// shared by all twelve kernels and invisible to pipe counters. The one
// never-varied element: __builtin_nontemporal_store. Mechanism: vmcnt
// retires IN ORDER (m135) and every iteration interleaves a store into the
// load queue; if NT stores bypass L2 and ack from the HBM controller
// (~600-1000 cyc), every counted wait for slice-t loads transitively blocks
// on an old store's ack -- distributed wait time, no pipe counter names it.
// The 6.3 TB/s copy ubench interleaves PLAIN stores (L2 ack ~200 cyc) and
// doesn't suffer. Fix: one line -- plain store. Output lines are write-once;
// L2 write-back absorbs 64 MB of streaming writes (fill kernel: 262 MB @
// 6.3 TB/s through the same path).
//
// Everything else is R16 byte-for-byte (best measured structure, kernel
// <=42.5 us): DCHUNK=16, DEPTH-5 LDS ring (30.7 KB), dist-3 DMA prefetch,
// stage(t+3) -> exact counted vmcnt -> s_barrier -> consume, shared 6-chunk
// staging (waves 0-1 stage 2 chunks via hasB), raw-max trick,
// clamp-replicate, H-max direct from LDS + halo column, W-max via 4
// shuffles, win[5]/cen[2] rings, VGPR<=64 cap.
//
// Tile: W=64 x H=16, DCHUNK=16 -> grid 8 x 32 x 4 = 1024 blocks, 256 thr.

#define THRESH 0.9f

constexpr int D = 64, H = 512, W = 512;
constexpr int HW = H * W;
constexpr int TW = 64;                    // tile width (floats)
constexpr int TH = 16;                    // tile height
constexpr int DCHUNK = 16;                // depth outputs per block
constexpr int HALO = 2;
constexpr int LROWS = TH + 2 * HALO;      // 20 staged rows
constexpr int RAWQ = TW / 4 + 2;          // 18 quads/row (linear, DMA dest)
constexpr int NQ = LROWS * RAWQ;          // 360 real quads
constexpr int SLOTS = 384;                // 6 chunks x 64 lanes
constexpr int DEPTH = 5;                  // LDS ring depth (dist-3 + WAR)
constexpr int NS = DCHUNK + 2 * HALO;     // 20 slices per block

typedef float floatx4 __attribute__((ext_vector_type(4)));
using gu32p = const __attribute__((address_space(1))) uint32_t*;
using lu32p = __attribute__((address_space(3))) uint32_t*;

__device__ __forceinline__ float4 max4(float4 a, float4 b) {
    return make_float4(fmaxf(a.x, b.x), fmaxf(a.y, b.y),
                       fmaxf(a.z, b.z), fmaxf(a.w, b.w));
}

// 5-tap sliding max for one quad. b = own (f4..f7), f2,f3 = left neighbor's
// .z,.w; f8,f9 = right neighbor's .x,.y. out[j] = max over [4c+j-2, 4c+j+2].
__device__ __forceinline__ float4 wmax5s(float f2, float f3, float4 b,
                                         float f8, float f9) {
    const float f4 = b.x, f5 = b.y, f6 = b.z, f7 = b.w;
    const float m45 = fmaxf(f4, f5);
    const float m56 = fmaxf(f5, f6);
    const float m345 = fmaxf(f3, m45);
    const float m456 = fmaxf(f4, m56);
    const float m567 = fmaxf(m56, f7);
    const float m678 = fmaxf(fmaxf(f6, f7), f8);
    float4 r;
    r.x = fmaxf(fmaxf(f2, f6), m345);
    r.y = fmaxf(fmaxf(f3, f7), m456);
    r.z = fmaxf(fmaxf(f4, f8), m567);
    r.w = fmaxf(fmaxf(f5, f9), m678);
    return r;
}

template <int N>
__device__ __forceinline__ void cwait() {   // counted vmcnt, no lgkm/exp wait
    asm volatile("s_waitcnt vmcnt(%0)" :: "n"(N) : "memory");
}

template <typename F, int... I>
__device__ __forceinline__ void static_for_impl(F&& f,
                                                std::integer_sequence<int, I...>) {
    (f(std::integral_constant<int, I>{}), ...);
}
template <int N, typename F>
__device__ __forceinline__ void static_for(F&& f) {
    static_for_impl(static_cast<F&&>(f), std::make_integer_sequence<int, N>{});
}

__global__ __launch_bounds__(256)
__attribute__((amdgpu_num_vgpr(64)))
void peak3d_kernel(const float* __restrict__ in, float* __restrict__ out) {
    __shared__ float4 raw[DEPTH][SLOTS];  // 5 x 6144 B = 30720 B

    const int tid = threadIdx.y * 16 + threadIdx.x;
    const int wid = tid >> 6;             // wave 0..3
    const int lane = tid & 63;
    const int tx = tid & 15;              // quad col 0..15
    const int ty = tid >> 4;              // row 0..15

    const int w0 = blockIdx.x * TW;
    const int h0 = blockIdx.y * TH;
    const int d0 = blockIdx.z * DCHUNK;

    // Staging: chunk A = wid (all waves), chunk B = 4+wid (waves 0,1 only).
    // Slot s -> (row, col) = (s/18, s%18); trash slots (>=360) clamp source.
    const bool hasB = (wid < 2);
    const int sA = min(64 * wid + lane, NQ - 1);
    const int sB = min(64 * (4 + wid) + lane, NQ - 1);
    const int rA = sA / RAWQ, cA = sA % RAWQ;
    const int rB = sB / RAWQ, cB = sB % RAWQ;
    const int ghA = min(max(h0 + rA - HALO, 0), H - 1);   // clamp-replicate
    const int gwA = min(max(w0 + 4 * cA - 4, 0), W - 4);
    const int ghB = min(max(h0 + rB - HALO, 0), H - 1);
    const int gwB = min(max(w0 + 4 * cB - 4, 0), W - 4);
    const int offA = ghA * W + gwA;
    const int offB = ghB * W + gwB;

    // Consume-phase indices (R13/R16 proven).
    const int rbase = ty * RAWQ + tx + 1;          // + rr*RAWQ, rr=0..4
    const bool isL = (tx == 0), isR = (tx == 15);
    const bool edgeW = (isL && w0 == 0) || (isR && w0 == W - TW);
    const int hbase = (ty * RAWQ + (isL ? 0 : RAWQ - 1)) * 2 + (isL ? 1 : 0);

    const float4 zero4 = make_float4(0.f, 0.f, 0.f, 0.f);
    float4 win[5];                        // HW-max ring, depth 5 (D window)
    float4 cen[2];                        // raw center ring, depth 2
#pragma unroll
    for (int k = 0; k < 5; ++k) win[k] = zero4;
    cen[0] = zero4; cen[1] = zero4;

    // Issue DMA for slice t into raw[t % DEPTH]. Wave-uniform LDS base.
    auto stage = [&](int t) {
        const int dd = min(max(d0 - HALO + t, 0), D - 1);
        const float* sp = in + dd * HW;
        float4* ldsb = &raw[t % DEPTH][0];
        __builtin_amdgcn_global_load_lds((gu32p)(sp + offA),
                                         (lu32p)(ldsb + 64 * wid), 16, 0, 0);
        if (hasB)
            __builtin_amdgcn_global_load_lds((gu32p)(sp + offB),
                                             (lu32p)(ldsb + 64 * (4 + wid)),
                                             16, 0, 0);
    };

    // Prologue: 3 slices in flight (dist-3).
    stage(0); stage(1); stage(2);

    static_for<NS>([&](auto tc) {
        constexpr int t = decltype(tc)::value;

        if (t + 3 < NS) stage(t + 3);     // keep 3 slices ahead

        // ---- counted wait: retire ONLY ops >= 3 iters old ----
        // After L(t): loads for slices (t, min(t+3, NS-1)] (2 or 1 ops each)
        // + stores for iters [max(4, t-3), t-1].
        constexpr int la = (t + 3 <= NS - 1) ? 3 : (NS - 1 - t);
        constexpr int lo = (t - 3 > 4) ? (t - 3) : 4;
        constexpr int sa = (t - 1 >= lo) ? (t - 1 - lo + 1) : 0;
        if (hasB) cwait<2 * la + sa>(); else cwait<la + sa>();
        asm volatile("s_barrier" ::: "memory");

        // ---- consume: H-max (5 rows) from LDS ring ----
        const float4* bp = &raw[t % DEPTH][0];
        const float4 r0q = bp[rbase + 0 * RAWQ];
        const float4 r1q = bp[rbase + 1 * RAWQ];
        const float4 r2q = bp[rbase + 2 * RAWQ];   // center row (raw)
        const float4 r3q = bp[rbase + 3 * RAWQ];
        const float4 r4q = bp[rbase + 4 * RAWQ];
        const float4 hv = max4(max4(max4(r0q, r1q), max4(r3q, r4q)), r2q);

        // ---- halo H-max: edge lanes only ----
        float2 h = make_float2(0.f, 0.f);
        if (isL || isR) {
            const float2* hp = reinterpret_cast<const float2*>(bp);
            const float2 e0 = hp[hbase + 0 * RAWQ * 2];
            const float2 e1 = hp[hbase + 1 * RAWQ * 2];
            const float2 e2 = hp[hbase + 2 * RAWQ * 2];
            const float2 e3 = hp[hbase + 3 * RAWQ * 2];
            const float2 e4 = hp[hbase + 4 * RAWQ * 2];
            h.x = fmaxf(fmaxf(fmaxf(e0.x, e1.x), fmaxf(e3.x, e4.x)), e2.x);
            h.y = fmaxf(fmaxf(fmaxf(e0.y, e1.y), fmaxf(e3.y, e4.y)), e2.y);
            if (edgeW) { h.x = 0.f; h.y = 0.f; }   // true OOB in W: pad 0
        }

        // ---- W-max via shuffles on H-maxed quads ----
        float f2 = __shfl_up(hv.z, 1);
        float f3 = __shfl_up(hv.w, 1);
        float f8 = __shfl_down(hv.x, 1);
        float f9 = __shfl_down(hv.y, 1);
        if (isL) { f2 = h.x; f3 = h.y; }
        if (isR) { f8 = h.x; f9 = h.y; }

        win[t % 5] = wmax5s(f2, f3, hv, f8, f9);   // HW-max, slice t

        // ---- D-max + strict-local-max + store (center = slice t-2) ----
        if (t >= 4) {
            const int dout = d0 + (t - 4);
            const float4 mp = max4(max4(max4(win[0], win[1]),
                                        max4(win[2], win[3])), win[4]);
            const float4 c = cen[t & 1];           // written at iter t-2
            floatx4 res;
            res.x = (c.x > THRESH && mp.x == c.x) ? c.x : 0.f;
            res.y = (c.y > THRESH && mp.y == c.y) ? c.y : 0.f;
            res.z = (c.z > THRESH && mp.z == c.z) ? c.z : 0.f;
            res.w = (c.w > THRESH && mp.w == c.w) ? c.w : 0.f;
            floatx4* op = reinterpret_cast<floatx4*>(
                out + (size_t)(dout * HW + (h0 + ty) * W + (w0 + 4 * tx)));
            *op = res;                    // PLAIN store (the A/B variable):
                                          // L2 write-back ack, not HBM ack.
        }
        cen[t & 1] = r2q;                          // write AFTER read above
    });
}

extern "C" void kernel_launch(void* const* d_in, const int* in_sizes, int n_in,
                              void* d_out, int out_size, void* d_ws, size_t ws_size,
                              hipStream_t stream) {
    const float* in = (const float*)d_in[0];
    float* out = (float*)d_out;
    dim3 grid(W / TW, H / TH, D / DCHUNK);    // 8 x 32 x 4 = 1024 blocks
    dim3 block(16, 16, 1);
    hipLaunchKernelGGL(peak3d_kernel, grid, block, 0, stream, in, out);
}

// Round 12
// 124.024 us; speedup vs baseline: 1.0016x; 1.0016x over previous
//
#include <hip/hip_runtime.h>
#include <stdint.h>
#include <utility>

// PostProcessor3D: threshold(>0.9) + 5x5x5 stride-1 maxpool + strict-local-max
// mask on [64,512,512] fp32.
//
// R23: OCCUPANCY RETEST UNDER PLAIN STORES. R22 (plain store, one-line A/B
// vs R16) pushed the kernel below the 41.3 us reset-fill floor -- it
// vanished from the top-5 (R16: <42.4 censored; R19: 44.5 measured). The
// occupancy axis was last tested in R20 (6 blk/CU -> 57 us REGRESSION) but
// that test was confounded: NT stores (slow HBM-side acks poisoning every
// in-order vmcnt chain -- more blocks = more poison, explaining the
// anti-correlation) plus a simultaneous loop-reorder (stage-after-barrier,
// DEPTH-4). With stores now acking at L2, R12's evidence stands: this chip
// sustains 3.6+ TB/s given enough in-flight memory ops. Single variable vs
// R22: DCHUNK 16->8 (grid 2048). LDS 30720 -> 5 resident blocks/CU
// (LDS-capped), 20 waves/CU ~62% (R22: 4 blocks, ~50%).
//
// Everything else R22 byte-for-byte: DEPTH-5 LDS ring, dist-3 DMA prefetch,
// stage(t+3) -> exact counted vmcnt -> s_barrier -> consume (vmcnt algebra
// parameterized by NS; NS=12 steady state = vmcnt(9), retires exactly
// through stage-group(t)), shared 6-chunk staging (hasB), raw-max trick,
// clamp-replicate, H-max direct from LDS + halo column, 4-shuffle W-max,
// win[5]/cen[2] rings, PLAIN stores, VGPR<=64 cap.
//
// Tile: W=64 x H=16, DCHUNK=8 -> grid 8 x 32 x 8 = 2048 blocks, 256 thr.

#define THRESH 0.9f

constexpr int D = 64, H = 512, W = 512;
constexpr int HW = H * W;
constexpr int TW = 64;                    // tile width (floats)
constexpr int TH = 16;                    // tile height
constexpr int DCHUNK = 8;                 // depth outputs per block
constexpr int HALO = 2;
constexpr int LROWS = TH + 2 * HALO;      // 20 staged rows
constexpr int RAWQ = TW / 4 + 2;          // 18 quads/row (linear, DMA dest)
constexpr int NQ = LROWS * RAWQ;          // 360 real quads
constexpr int SLOTS = 384;                // 6 chunks x 64 lanes
constexpr int DEPTH = 5;                  // LDS ring depth (dist-3 + WAR)
constexpr int NS = DCHUNK + 2 * HALO;     // 12 slices per block

typedef float floatx4 __attribute__((ext_vector_type(4)));
using gu32p = const __attribute__((address_space(1))) uint32_t*;
using lu32p = __attribute__((address_space(3))) uint32_t*;

__device__ __forceinline__ float4 max4(float4 a, float4 b) {
    return make_float4(fmaxf(a.x, b.x), fmaxf(a.y, b.y),
                       fmaxf(a.z, b.z), fmaxf(a.w, b.w));
}

// 5-tap sliding max for one quad. b = own (f4..f7), f2,f3 = left neighbor's
// .z,.w; f8,f9 = right neighbor's .x,.y. out[j] = max over [4c+j-2, 4c+j+2].
__device__ __forceinline__ float4 wmax5s(float f2, float f3, float4 b,
                                         float f8, float f9) {
    const float f4 = b.x, f5 = b.y, f6 = b.z, f7 = b.w;
    const float m45 = fmaxf(f4, f5);
    const float m56 = fmaxf(f5, f6);
    const float m345 = fmaxf(f3, m45);
    const float m456 = fmaxf(f4, m56);
    const float m567 = fmaxf(m56, f7);
    const float m678 = fmaxf(fmaxf(f6, f7), f8);
    float4 r;
    r.x = fmaxf(fmaxf(f2, f6), m345);
    r.y = fmaxf(fmaxf(f3, f7), m456);
    r.z = fmaxf(fmaxf(f4, f8), m567);
    r.w = fmaxf(fmaxf(f5, f9), m678);
    return r;
}

template <int N>
__device__ __forceinline__ void cwait() {   // counted vmcnt, no lgkm/exp wait
    asm volatile("s_waitcnt vmcnt(%0)" :: "n"(N) : "memory");
}

template <typename F, int... I>
__device__ __forceinline__ void static_for_impl(F&& f,
                                                std::integer_sequence<int, I...>) {
    (f(std::integral_constant<int, I>{}), ...);
}
template <int N, typename F>
__device__ __forceinline__ void static_for(F&& f) {
    static_for_impl(static_cast<F&&>(f), std::make_integer_sequence<int, N>{});
}

__global__ __launch_bounds__(256)
__attribute__((amdgpu_num_vgpr(64)))
void peak3d_kernel(const float* __restrict__ in, float* __restrict__ out) {
    __shared__ float4 raw[DEPTH][SLOTS];  // 5 x 6144 B = 30720 B

    const int tid = threadIdx.y * 16 + threadIdx.x;
    const int wid = tid >> 6;             // wave 0..3
    const int lane = tid & 63;
    const int tx = tid & 15;              // quad col 0..15
    const int ty = tid >> 4;              // row 0..15

    const int w0 = blockIdx.x * TW;
    const int h0 = blockIdx.y * TH;
    const int d0 = blockIdx.z * DCHUNK;

    // Staging: chunk A = wid (all waves), chunk B = 4+wid (waves 0,1 only).
    // Slot s -> (row, col) = (s/18, s%18); trash slots (>=360) clamp source.
    const bool hasB = (wid < 2);
    const int sA = min(64 * wid + lane, NQ - 1);
    const int sB = min(64 * (4 + wid) + lane, NQ - 1);
    const int rA = sA / RAWQ, cA = sA % RAWQ;
    const int rB = sB / RAWQ, cB = sB % RAWQ;
    const int ghA = min(max(h0 + rA - HALO, 0), H - 1);   // clamp-replicate
    const int gwA = min(max(w0 + 4 * cA - 4, 0), W - 4);
    const int ghB = min(max(h0 + rB - HALO, 0), H - 1);
    const int gwB = min(max(w0 + 4 * cB - 4, 0), W - 4);
    const int offA = ghA * W + gwA;
    const int offB = ghB * W + gwB;

    // Consume-phase indices (R13/R16/R22 proven).
    const int rbase = ty * RAWQ + tx + 1;          // + rr*RAWQ, rr=0..4
    const bool isL = (tx == 0), isR = (tx == 15);
    const bool edgeW = (isL && w0 == 0) || (isR && w0 == W - TW);
    const int hbase = (ty * RAWQ + (isL ? 0 : RAWQ - 1)) * 2 + (isL ? 1 : 0);

    const float4 zero4 = make_float4(0.f, 0.f, 0.f, 0.f);
    float4 win[5];                        // HW-max ring, depth 5 (D window)
    float4 cen[2];                        // raw center ring, depth 2
#pragma unroll
    for (int k = 0; k < 5; ++k) win[k] = zero4;
    cen[0] = zero4; cen[1] = zero4;

    // Issue DMA for slice t into raw[t % DEPTH]. Wave-uniform LDS base.
    auto stage = [&](int t) {
        const int dd = min(max(d0 - HALO + t, 0), D - 1);
        const float* sp = in + dd * HW;
        float4* ldsb = &raw[t % DEPTH][0];
        __builtin_amdgcn_global_load_lds((gu32p)(sp + offA),
                                         (lu32p)(ldsb + 64 * wid), 16, 0, 0);
        if (hasB)
            __builtin_amdgcn_global_load_lds((gu32p)(sp + offB),
                                             (lu32p)(ldsb + 64 * (4 + wid)),
                                             16, 0, 0);
    };

    // Prologue: 3 slices in flight (dist-3).
    stage(0); stage(1); stage(2);

    static_for<NS>([&](auto tc) {
        constexpr int t = decltype(tc)::value;

        if (t + 3 < NS) stage(t + 3);     // keep 3 slices ahead

        // ---- counted wait: retire ONLY ops >= 3 iters old ----
        // After L(t): loads for slices (t, min(t+3, NS-1)] (2 or 1 ops each)
        // + stores for iters [max(4, t-3), t-1].
        constexpr int la = (t + 3 <= NS - 1) ? 3 : (NS - 1 - t);
        constexpr int lo = (t - 3 > 4) ? (t - 3) : 4;
        constexpr int sa = (t - 1 >= lo) ? (t - 1 - lo + 1) : 0;
        if (hasB) cwait<2 * la + sa>(); else cwait<la + sa>();
        asm volatile("s_barrier" ::: "memory");

        // ---- consume: H-max (5 rows) from LDS ring ----
        const float4* bp = &raw[t % DEPTH][0];
        const float4 r0q = bp[rbase + 0 * RAWQ];
        const float4 r1q = bp[rbase + 1 * RAWQ];
        const float4 r2q = bp[rbase + 2 * RAWQ];   // center row (raw)
        const float4 r3q = bp[rbase + 3 * RAWQ];
        const float4 r4q = bp[rbase + 4 * RAWQ];
        const float4 hv = max4(max4(max4(r0q, r1q), max4(r3q, r4q)), r2q);

        // ---- halo H-max: edge lanes only ----
        float2 h = make_float2(0.f, 0.f);
        if (isL || isR) {
            const float2* hp = reinterpret_cast<const float2*>(bp);
            const float2 e0 = hp[hbase + 0 * RAWQ * 2];
            const float2 e1 = hp[hbase + 1 * RAWQ * 2];
            const float2 e2 = hp[hbase + 2 * RAWQ * 2];
            const float2 e3 = hp[hbase + 3 * RAWQ * 2];
            const float2 e4 = hp[hbase + 4 * RAWQ * 2];
            h.x = fmaxf(fmaxf(fmaxf(e0.x, e1.x), fmaxf(e3.x, e4.x)), e2.x);
            h.y = fmaxf(fmaxf(fmaxf(e0.y, e1.y), fmaxf(e3.y, e4.y)), e2.y);
            if (edgeW) { h.x = 0.f; h.y = 0.f; }   // true OOB in W: pad 0
        }

        // ---- W-max via shuffles on H-maxed quads ----
        float f2 = __shfl_up(hv.z, 1);
        float f3 = __shfl_up(hv.w, 1);
        float f8 = __shfl_down(hv.x, 1);
        float f9 = __shfl_down(hv.y, 1);
        if (isL) { f2 = h.x; f3 = h.y; }
        if (isR) { f8 = h.x; f9 = h.y; }

        win[t % 5] = wmax5s(f2, f3, hv, f8, f9);   // HW-max, slice t

        // ---- D-max + strict-local-max + store (center = slice t-2) ----
        if (t >= 4) {
            const int dout = d0 + (t - 4);
            const float4 mp = max4(max4(max4(win[0], win[1]),
                                        max4(win[2], win[3])), win[4]);
            const float4 c = cen[t & 1];           // written at iter t-2
            floatx4 res;
            res.x = (c.x > THRESH && mp.x == c.x) ? c.x : 0.f;
            res.y = (c.y > THRESH && mp.y == c.y) ? c.y : 0.f;
            res.z = (c.z > THRESH && mp.z == c.z) ? c.z : 0.f;
            res.w = (c.w > THRESH && mp.w == c.w) ? c.w : 0.f;
            floatx4* op = reinterpret_cast<floatx4*>(
                out + (size_t)(dout * HW + (h0 + ty) * W + (w0 + 4 * tx)));
            *op = res;                    // plain store: L2 write-back ack
        }
        cen[t & 1] = r2q;                          // write AFTER read above
    });
}

extern "C" void kernel_launch(void* const* d_in, const int* in_sizes, int n_in,
                              void* d_out, int out_size, void* d_ws, size_t ws_size,
                              hipStream_t stream) {
    const float* in = (const float*)d_in[0];
    float* out = (float*)d_out;
    dim3 grid(W / TW, H / TH, D / DCHUNK);    // 8 x 32 x 8 = 2048 blocks
    dim3 block(16, 16, 1);
    hipLaunchKernelGGL(peak3d_kernel, grid, block, 0, stream, in, out);
}

// Round 13
// 117.073 us; speedup vs baseline: 1.0611x; 1.0594x over previous
//
#include <hip/hip_runtime.h>
#include <stdint.h>
#include <utility>

// PostProcessor3D: threshold(>0.9) + 5x5x5 stride-1 maxpool + strict-local-max
// mask on [64,512,512] fp32.
//
// R24: FULL-WIDTH SLABS -- make every HBM transaction >=1KB contiguous.
// 12-round invariant: realized HBM BW pinned at 2.7-3.6 TB/s (fill: 6.3)
// across every sync scheme / prefetch depth / data path / occupancy. The one
// shared property vs the 6.3 TB/s ubenches: short segments (288B staging
// fragments at 2KB stride). DRAM efficiency collapses on sub-512B scattered
// bursts -- explains work-proportional cost, structure-insensitivity, and
// "no pipe >50%" (loss is DRAM-level, not request-count). Also: plain-store
// rounds (R22/R23) consistently cost ~7us at the GRADED bench level vs NT
// rounds -> NT stores restored.
//  (a) Tile = 4 FULL rows x W=512: staging = 8 full rows/slice = 16KB in
//      16 wave-DMAs of 1KB contiguous each (4/wave, uniform, no trash).
//      Stores: 8KB contiguous per block-slice. No W-halo anywhere.
//  (b) Wave w owns row h0+w. Lane holds 2 quads (qc=lane, lane+64); W-max
//      seam between pipes via 2 lane-broadcast shuffles; true W edges -> 0.
//  (c) XCD remap: grid 512 linear; xcd=b&7 owns a contiguous 64-row band
//      (all z) -> H-halo (2x) and z-halo (1.25x) refetches are same-XCD
//      L2 hits -> FETCH stays near the 67MB minimum.
//  (d) R16 proven skeleton: DEPTH-5 LDS ring (80KB -> 2 blk/CU), dist-3 DMA,
//      stage(t+3) -> exact counted vmcnt -> s_barrier -> consume. vmcnt
//      re-derived for 4 loads + 2 stores/iter: N = 4*la + 2*sc (steady 18;
//      checked t=0,4,5,8,17,18,19). win[5]/cen[2] rings per pipe, raw-max
//      trick, clamp-replicate in H and D, NT stores. No VGPR cap (grid-bound).
//
// Tile: W=512 x H=4, DCHUNK=16 -> 512 blocks (linear, XCD-remapped), 256 thr.

#define THRESH 0.9f

constexpr int D = 64, H = 512, W = 512;
constexpr int HW = H * W;
constexpr int TH = 4;                     // output rows per block
constexpr int DCHUNK = 16;                // depth outputs per block
constexpr int HALO = 2;
constexpr int LROWS = TH + 2 * HALO;      // 8 staged full rows
constexpr int QROW = W / 4;               // 128 quads per row
constexpr int NQ = LROWS * QROW;          // 1024 slots (= 4 x 256, exact)
constexpr int DEPTH = 5;                  // LDS ring depth (dist-3 + WAR)
constexpr int NS = DCHUNK + 2 * HALO;     // 20 slices per block

typedef float floatx4 __attribute__((ext_vector_type(4)));
using gu32p = const __attribute__((address_space(1))) uint32_t*;
using lu32p = __attribute__((address_space(3))) uint32_t*;

__device__ __forceinline__ float4 max4(float4 a, float4 b) {
    return make_float4(fmaxf(a.x, b.x), fmaxf(a.y, b.y),
                       fmaxf(a.z, b.z), fmaxf(a.w, b.w));
}

// 5-tap sliding max for one quad. b = own (f4..f7), f2,f3 = left neighbor's
// .z,.w; f8,f9 = right neighbor's .x,.y. out[j] = max over [4c+j-2, 4c+j+2].
__device__ __forceinline__ float4 wmax5s(float f2, float f3, float4 b,
                                         float f8, float f9) {
    const float f4 = b.x, f5 = b.y, f6 = b.z, f7 = b.w;
    const float m45 = fmaxf(f4, f5);
    const float m56 = fmaxf(f5, f6);
    const float m345 = fmaxf(f3, m45);
    const float m456 = fmaxf(f4, m56);
    const float m567 = fmaxf(m56, f7);
    const float m678 = fmaxf(fmaxf(f6, f7), f8);
    float4 r;
    r.x = fmaxf(fmaxf(f2, f6), m345);
    r.y = fmaxf(fmaxf(f3, f7), m456);
    r.z = fmaxf(fmaxf(f4, f8), m567);
    r.w = fmaxf(fmaxf(f5, f9), m678);
    return r;
}

template <int N>
__device__ __forceinline__ void cwait() {   // counted vmcnt, no lgkm/exp wait
    asm volatile("s_waitcnt vmcnt(%0)" :: "n"(N) : "memory");
}

template <typename F, int... I>
__device__ __forceinline__ void static_for_impl(F&& f,
                                                std::integer_sequence<int, I...>) {
    (f(std::integral_constant<int, I>{}), ...);
}
template <int N, typename F>
__device__ __forceinline__ void static_for(F&& f) {
    static_for_impl(static_cast<F&&>(f), std::make_integer_sequence<int, N>{});
}

__global__ __launch_bounds__(256)
void peak3d_kernel(const float* __restrict__ in, float* __restrict__ out) {
    __shared__ float4 raw[DEPTH][NQ];     // 5 x 16384 B = 81920 B

    const int tid = threadIdx.x;          // 0..255
    const int wid = tid >> 6;             // wave 0..3 (owns output row h0+wid)
    const int lane = tid & 63;

    // XCD-aware tile remap: xcd (b&7) owns rows [xcd*64, xcd*64+64) x all z.
    const int b = blockIdx.x;             // 0..511
    const int xcd = b & 7;
    const int idx = b >> 3;               // 0..63
    const int h0 = (xcd * 16 + (idx >> 2)) * TH;   // band-contiguous in y
    const int d0 = (idx & 3) * DCHUNK;

    // Staging: 4 slots/thread at s = tid + 256g. Slot s -> (row s>>7,
    // quad s&127). Each wave-instr spans 64 consecutive slots in one row
    // -> 1 KB contiguous global. H clamp-replicate.
    int off[4];
#pragma unroll
    for (int g = 0; g < 4; ++g) {
        const int s = tid + 256 * g;
        const int r = s >> 7;
        const int qc = s & 127;
        const int gh = min(max(h0 + r - HALO, 0), H - 1);
        off[g] = gh * W + 4 * qc;
    }

    const float4 zero4 = make_float4(0.f, 0.f, 0.f, 0.f);
    float4 winA[5], winB[5];              // HW-max rings (D window), 2 pipes
    float4 cenA[2], cenB[2];              // raw center rings
#pragma unroll
    for (int k = 0; k < 5; ++k) { winA[k] = zero4; winB[k] = zero4; }
    cenA[0] = zero4; cenA[1] = zero4; cenB[0] = zero4; cenB[1] = zero4;

    // Issue 4 DMA loads (1 KB contiguous each) for slice t into raw[t%5].
    auto stage = [&](int t) {
        const int dd = min(max(d0 - HALO + t, 0), D - 1);
        const float* sp = in + dd * HW;
        float4* ldsb = &raw[t % DEPTH][0];
#pragma unroll
        for (int g = 0; g < 4; ++g)
            __builtin_amdgcn_global_load_lds((gu32p)(sp + off[g]),
                                             (lu32p)(ldsb + 64 * wid + 256 * g),
                                             16, 0, 0);
    };

    // Prologue: 3 slices in flight (dist-3).
    stage(0); stage(1); stage(2);

    static_for<NS>([&](auto tc) {
        constexpr int t = decltype(tc)::value;

        if (t + 3 < NS) stage(t + 3);     // keep 3 slices ahead

        // ---- counted wait: retire ONLY ops >= 3 iters old ----
        // Newer than group(t): groups {t+1,t+2,t+3} within [0,NS-1] (4 ops
        // each) + stores of iters [max(4,t-3), t-1] (2 ops each).
        constexpr int la = (NS - 1 - t < 3) ? (NS - 1 - t) : 3;
        constexpr int lo = (t - 3 > 4) ? (t - 3) : 4;
        constexpr int sc = (t - 1 >= lo) ? (t - 1 - lo + 1) : 0;
        cwait<4 * la + 2 * sc>();
        asm volatile("s_barrier" ::: "memory");

        // ---- consume: 5-row H-max per pipe from LDS (stage rows wid..wid+4) ----
        const float4* bp = &raw[t % DEPTH][0];
        const float4 a0 = bp[(wid + 0) * QROW + lane];
        const float4 a1 = bp[(wid + 1) * QROW + lane];
        const float4 a2 = bp[(wid + 2) * QROW + lane];       // center (raw)
        const float4 a3 = bp[(wid + 3) * QROW + lane];
        const float4 a4 = bp[(wid + 4) * QROW + lane];
        const float4 hvA = max4(max4(max4(a0, a1), max4(a3, a4)), a2);

        const float4 b0 = bp[(wid + 0) * QROW + 64 + lane];
        const float4 b1 = bp[(wid + 1) * QROW + 64 + lane];
        const float4 b2q = bp[(wid + 2) * QROW + 64 + lane]; // center (raw)
        const float4 b3 = bp[(wid + 3) * QROW + 64 + lane];
        const float4 b4 = bp[(wid + 4) * QROW + 64 + lane];
        const float4 hvB = max4(max4(max4(b0, b1), max4(b3, b4)), b2q);

        // ---- W-max taps: intra-pipe shuffles + cross-pipe seam ----
        float fa2 = __shfl_up(hvA.z, 1), fa3 = __shfl_up(hvA.w, 1);
        float fa8 = __shfl_down(hvA.x, 1), fa9 = __shfl_down(hvA.y, 1);
        const float sb0x = __shfl(hvB.x, 0), sb0y = __shfl(hvB.y, 0);
        if (lane == 0)  { fa2 = 0.f; fa3 = 0.f; }            // true W edge
        if (lane == 63) { fa8 = sb0x; fa9 = sb0y; }          // seam qc 63|64

        float fb2 = __shfl_up(hvB.z, 1), fb3 = __shfl_up(hvB.w, 1);
        float fb8 = __shfl_down(hvB.x, 1), fb9 = __shfl_down(hvB.y, 1);
        const float sa63z = __shfl(hvA.z, 63), sa63w = __shfl(hvA.w, 63);
        if (lane == 0)  { fb2 = sa63z; fb3 = sa63w; }        // seam qc 63|64
        if (lane == 63) { fb8 = 0.f; fb9 = 0.f; }            // true W edge

        winA[t % 5] = wmax5s(fa2, fa3, hvA, fa8, fa9);       // HW-max slice t
        winB[t % 5] = wmax5s(fb2, fb3, hvB, fb8, fb9);

        // ---- D-max + strict-local-max + store (center = slice t-2) ----
        if (t >= 4) {
            const int dout = d0 + (t - 4);
            const size_t rowb = (size_t)(dout * HW + (h0 + wid) * W);

            const float4 mpA = max4(max4(max4(winA[0], winA[1]),
                                         max4(winA[2], winA[3])), winA[4]);
            const float4 cA = cenA[t & 1];         // written at iter t-2
            floatx4 rA;
            rA.x = (cA.x > THRESH && mpA.x == cA.x) ? cA.x : 0.f;
            rA.y = (cA.y > THRESH && mpA.y == cA.y) ? cA.y : 0.f;
            rA.z = (cA.z > THRESH && mpA.z == cA.z) ? cA.z : 0.f;
            rA.w = (cA.w > THRESH && mpA.w == cA.w) ? cA.w : 0.f;
            __builtin_nontemporal_store(rA,
                reinterpret_cast<floatx4*>(out + rowb + 4 * lane));

            const float4 mpB = max4(max4(max4(winB[0], winB[1]),
                                         max4(winB[2], winB[3])), winB[4]);
            const float4 cB = cenB[t & 1];
            floatx4 rB;
            rB.x = (cB.x > THRESH && mpB.x == cB.x) ? cB.x : 0.f;
            rB.y = (cB.y > THRESH && mpB.y == cB.y) ? cB.y : 0.f;
            rB.z = (cB.z > THRESH && mpB.z == cB.z) ? cB.z : 0.f;
            rB.w = (cB.w > THRESH && mpB.w == cB.w) ? cB.w : 0.f;
            __builtin_nontemporal_store(rB,
                reinterpret_cast<floatx4*>(out + rowb + 256 + 4 * lane));
        }
        cenA[t & 1] = a2;                          // write AFTER read above
        cenB[t & 1] = b2q;
    });
}

extern "C" void kernel_launch(void* const* d_in, const int* in_sizes, int n_in,
                              void* d_out, int out_size, void* d_ws, size_t ws_size,
                              hipStream_t stream) {
    const float* in = (const float*)d_in[0];
    float* out = (float*)d_out;
    dim3 grid(512, 1, 1);                 // linear; XCD-remapped in-kernel
    dim3 block(256, 1, 1);
    hipLaunchKernelGGL(peak3d_kernel, grid, block, 0, stream, in, out);
}